// Round 5
// baseline (6697.440 us; speedup 1.0000x reference)
//
#include <hip/hip_runtime.h>
#include <hip/hip_bf16.h>

#define NT 128
#define NE 256
#define ND 256

__device__ __forceinline__ float fast_tanh(float x) {
    const float e = __expf(2.f * x);
    return __builtin_fmaf(-2.f, __fdividef(1.f, e + 1.f), 1.f);
}
__device__ __forceinline__ float fast_sigm(float x) {
    return __fdividef(1.f, 1.f + __expf(-x));
}
__device__ __forceinline__ void fma4(float4& a, float s, const float4 b) {
    a.x += s * b.x; a.y += s * b.y; a.z += s * b.z; a.w += s * b.w;
}
__device__ __forceinline__ unsigned short f2bf(float f) {   // RNE
    unsigned int u = __float_as_uint(f);
    return (unsigned short)((u + 0x7FFFu + ((u >> 16) & 1u)) >> 16);
}
// unpack 4 bf16 (packed in uint2) -> float4. elem0 = low half of .x
__device__ __forceinline__ float4 unpk(uint2 u) {
    float4 r;
    r.x = __uint_as_float(u.x << 16);
    r.y = __uint_as_float(u.x & 0xFFFF0000u);
    r.z = __uint_as_float(u.y << 16);
    r.w = __uint_as_float(u.y & 0xFFFF0000u);
    return r;
}
__device__ __forceinline__ uint2 pk4(float4 v) {
    uint2 u;
    u.x = (unsigned int)f2bf(v.x) | ((unsigned int)f2bf(v.y) << 16);
    u.y = (unsigned int)f2bf(v.z) | ((unsigned int)f2bf(v.w) << 16);
    return u;
}

// ---- prep: w1 hc-half -> bf16 (blocks 0..511); bias sum (block 512)
__global__ __launch_bounds__(256) void prep_w1_bias(
    const float* __restrict__ w1, const float* __restrict__ bih,
    const float* __restrict__ bhh, unsigned short* __restrict__ w1bf,
    float* __restrict__ biasg)
{
    const int t = threadIdx.x, blk = blockIdx.x;
    if (blk < 512) {
        const int idx = blk * 256 + t;
        w1bf[idx] = f2bf(w1[idx]);
    } else {
        for (int g = t; g < 1024; g += 256) biasg[g] = bih[g] + bhh[g];
    }
}

// ---- transpose whh[1024][256] -> whhT_bf16[256][1024]
__global__ __launch_bounds__(256) void transpose_whh_bf(
    const float* __restrict__ whh, unsigned short* __restrict__ whhT)
{
    __shared__ float tile[64][65];
    const int t = threadIdx.x;
    const int bi = blockIdx.x >> 2;
    const int bj = blockIdx.x & 3;
    #pragma unroll
    for (int k = 0; k < 16; ++k) {
        const int idx = k * 256 + t, r = idx >> 6, c = idx & 63;
        tile[r][c] = whh[(size_t)(bi * 64 + r) * 256 + bj * 64 + c];
    }
    __syncthreads();
    #pragma unroll
    for (int k = 0; k < 16; ++k) {
        const int idx = k * 256 + t, r = idx >> 6, c = idx & 63;
        whhT[(size_t)(bj * 64 + r) * 1024 + bi * 64 + c] = f2bf(tile[c][r]);
    }
}

// ---- pre[row][j] = b1[j] + sum_i enc[row][i] * attn_w1[512+i][j]; bf16 out
__global__ __launch_bounds__(256) void pre_enc_kernel(
    const float* __restrict__ enc, const float* __restrict__ w1,
    const float* __restrict__ b1, unsigned short* __restrict__ prebf)
{
    __shared__ __align__(16) float encs[8][256];
    const int t = threadIdx.x;
    const size_t r0 = (size_t)blockIdx.x * 8;
    for (int k = t; k < 512; k += 256) {
        const int rl = k >> 6, i4 = (k & 63) * 4;
        *(float4*)&encs[rl][i4] = *(const float4*)(enc + (r0 + rl) * 256 + i4);
    }
    __syncthreads();
    const int rl = t >> 5;
    const int j0 = (t & 31) * 8;
    float4 a0 = *(const float4*)(b1 + j0);
    float4 a1 = *(const float4*)(b1 + j0 + 4);
    const float* wp = w1 + (size_t)512 * 256 + j0;
    #pragma unroll 2
    for (int i = 0; i < 256; i += 4) {
        const float4 e4 = *(const float4*)&encs[rl][i];
        const float* w_i = wp + (size_t)i * 256;
        float4 wa, wb;
        wa = *(const float4*)(w_i);        wb = *(const float4*)(w_i + 4);
        fma4(a0, e4.x, wa); fma4(a1, e4.x, wb);
        wa = *(const float4*)(w_i + 256);  wb = *(const float4*)(w_i + 260);
        fma4(a0, e4.y, wa); fma4(a1, e4.y, wb);
        wa = *(const float4*)(w_i + 512);  wb = *(const float4*)(w_i + 516);
        fma4(a0, e4.z, wa); fma4(a1, e4.z, wb);
        wa = *(const float4*)(w_i + 768);  wb = *(const float4*)(w_i + 772);
        fma4(a0, e4.w, wa); fma4(a1, e4.w, wb);
    }
    unsigned short* op = prebf + (r0 + rl) * 256 + j0;
    const uint2 u0 = pk4(a0), u1 = pk4(a1);
    *(uint2*)op = u0;
    *(uint2*)(op + 4) = u1;
}

// ---- main scan: 256 WGs x 1024 threads, 2 batch rows per WG.
// enc + pre + yhist staged ONCE (LDS + registers); per-step external
// traffic is weights only (w1bf 256KB + whhT 512KB per CU from L2).
__global__ __launch_bounds__(1024, 4) void decoder_main(
    const float* __restrict__ enc, const float* __restrict__ yhist,
    const unsigned short* __restrict__ prebf,
    const unsigned short* __restrict__ w1bf,
    const float* __restrict__ w2g, const unsigned short* __restrict__ whhT,
    const float* __restrict__ wih, const float* __restrict__ biasg,
    const float* __restrict__ fcw, const float* __restrict__ fcb,
    const float* __restrict__ fcfw, const float* __restrict__ fcfb,
    float* __restrict__ out)
{
    __shared__ __align__(16) unsigned short encs[2][64][256]; // 64KB: s%16<8 rows
    __shared__ __align__(16) float part[8192];                // 32KB union A/C/E
    __shared__ __align__(16) float hc2[512][2];               // 4KB [i][r]
    __shared__ __align__(16) float prehc[2][256];             // 2KB
    __shared__ __align__(16) float scores[2][128];            // 1KB (attn in-place)
    __shared__ __align__(16) float ctx[2][256];               // 2KB
    __shared__ __align__(16) float w2s[256];                  // 1KB
    __shared__ __align__(16) float fcws[258];
    __shared__ __align__(16) float wihs[1024];                // 4KB
    __shared__ __align__(16) float biass[1024];               // 4KB
    __shared__ __align__(16) float ys[2][128];                // 1KB
    __shared__ float red[16];
    __shared__ float ytil[2];

    const int t = threadIdx.x;
    const int lane = t & 63;
    const int wv = t >> 6;           // wave 0..15
    const int b0 = blockIdx.x * 2;

    // ---- one-time staging
    ((float*)hc2)[t] = 0.f;
    wihs[t] = wih[t];
    biass[t] = biasg[t];
    if (t < 256) w2s[t] = w2g[t];
    if (t < 258) fcws[t] = (t < 257) ? fcw[t] : fcb[0];
    if (t < 256) ys[t >> 7][t & 127] = yhist[(size_t)(b0 + (t >> 7)) * NT + (t & 127)];
    // encs LDS: rows with (s&15)<8 -> lds row (s>>4)*8 + (s&7)
    #pragma unroll
    for (int k = 0; k < 8; ++k) {
        const int idx = t + k * 1024;
        const int r = idx >> 12, lr = (idx >> 6) & 63, eg = idx & 63;
        const int s = (lr >> 3) * 16 + (lr & 7);
        const float4 v = *(const float4*)(enc + ((size_t)(b0 + r) * NT + s) * NE + eg * 4);
        *(uint2*)&encs[r][lr][eg * 4] = pk4(v);
    }
    // enc register half: thread (r2, sl, e4) holds s2 in [8,16)
    const int r2 = t >> 9, sl = (t >> 6) & 7, e4 = (t & 63) * 4;
    uint2 er[8];
    #pragma unroll
    for (int q = 0; q < 8; ++q) {
        const int s = sl * 16 + 8 + q;
        const float4 v = *(const float4*)(enc + ((size_t)(b0 + r2) * NT + s) * NE + e4);
        er[q] = pk4(v);
    }
    // pre register slice: thread (s_, jc) holds j = i*32 + jc*4, i<8, both rows
    const int s_ = t >> 3, jc = t & 7;
    uint2 pr0[8], pr1[8];
    {
        const unsigned short* pp = prebf + ((size_t)b0 * NT + s_) * NE + jc * 4;
        #pragma unroll
        for (int i = 0; i < 8; ++i) {
            pr0[i] = *(const uint2*)(pp + i * 32);
            pr1[i] = *(const uint2*)(pp + (size_t)NT * NE + i * 32);
        }
    }
    __syncthreads();

    #pragma unroll 1
    for (int ts = 0; ts < NT; ++ts) {
        // ---- A: prehc partials. wave wv: i in [wv*32,+32) of K=512, j=lane*4
        {
            float4 a0 = {0,0,0,0}, a1 = {0,0,0,0};
            const unsigned short* wp = w1bf + (size_t)(wv * 32) * 256 + lane * 4;
            #pragma unroll 8
            for (int i = 0; i < 32; ++i) {
                const float4 w4 = unpk(*(const uint2*)(wp + (size_t)i * 256));
                const float2 h2 = *(const float2*)&hc2[wv * 32 + i][0];
                fma4(a0, h2.x, w4);
                fma4(a1, h2.y, w4);
            }
            *(float4*)&part[(wv * 2 + 0) * 256 + lane * 4] = a0;
            *(float4*)&part[(wv * 2 + 1) * 256 + lane * 4] = a1;
        }
        __syncthreads();
        if (t < 512) {        // reduce A
            const int r = t >> 8, j = t & 255;
            float s = 0.f;
            #pragma unroll
            for (int w = 0; w < 16; ++w) s += part[(w * 2 + r) * 256 + j];
            prehc[r][j] = s;
        }
        __syncthreads();

        // ---- B: scores from register-held pre
        {
            float a0 = 0.f, a1 = 0.f;
            #pragma unroll
            for (int i = 0; i < 8; ++i) {
                const int j = i * 32 + jc * 4;
                const float4 wv4 = *(const float4*)&w2s[j];
                const float4 h0 = *(const float4*)&prehc[0][j];
                const float4 h1 = *(const float4*)&prehc[1][j];
                const float4 q0 = unpk(pr0[i]);
                const float4 q1 = unpk(pr1[i]);
                a0 += fast_tanh(q0.x + h0.x) * wv4.x + fast_tanh(q0.y + h0.y) * wv4.y
                    + fast_tanh(q0.z + h0.z) * wv4.z + fast_tanh(q0.w + h0.w) * wv4.w;
                a1 += fast_tanh(q1.x + h1.x) * wv4.x + fast_tanh(q1.y + h1.y) * wv4.y
                    + fast_tanh(q1.z + h1.z) * wv4.z + fast_tanh(q1.w + h1.w) * wv4.w;
            }
            a0 += __shfl_xor(a0, 1); a0 += __shfl_xor(a0, 2); a0 += __shfl_xor(a0, 4);
            a1 += __shfl_xor(a1, 1); a1 += __shfl_xor(a1, 2); a1 += __shfl_xor(a1, 4);
            if (jc == 0) { scores[0][s_] = a0; scores[1][s_] = a1; }
        }
        __syncthreads();

        // ---- softmax in-place (scores -> attn)
        if (t < 128) {
            const int r = t >> 6, l = t & 63;
            const float v0 = scores[r][l], v1 = scores[r][l + 64];
            float m = fmaxf(v0, v1);
            #pragma unroll
            for (int off = 32; off; off >>= 1) m = fmaxf(m, __shfl_xor(m, off));
            const float e0 = __expf(v0 - m), e1 = __expf(v1 - m);
            float sum = e0 + e1;
            #pragma unroll
            for (int off = 32; off; off >>= 1) sum += __shfl_xor(sum, off);
            const float inv = __fdividef(1.f, sum);
            scores[r][l] = e0 * inv;
            scores[r][l + 64] = e1 * inv;
        }
        __syncthreads();

        // ---- C: ctx partials from LDS(8 rows) + regs(8 rows)
        {
            float4 acc = {0.f, 0.f, 0.f, 0.f};
            #pragma unroll
            for (int q = 0; q < 8; ++q) {
                const float a = scores[r2][sl * 16 + q];
                const uint2 ev = *(const uint2*)&encs[r2][sl * 8 + q][e4];
                fma4(acc, a, unpk(ev));
            }
            #pragma unroll
            for (int q = 0; q < 8; ++q) {
                const float a = scores[r2][sl * 16 + 8 + q];
                fma4(acc, a, unpk(er[q]));
            }
            *(float4*)&part[(sl * 2 + r2) * 256 + e4] = acc;
        }
        __syncthreads();
        if (t < 512) {        // reduce C + y_tilde partial
            const int r = t >> 8, e = t & 255;
            float v = 0.f;
            #pragma unroll
            for (int slc = 0; slc < 8; ++slc) v += part[(slc * 2 + r) * 256 + e];
            ctx[r][e] = v;
            float p = v * fcws[e];
            #pragma unroll
            for (int off = 32; off; off >>= 1) p += __shfl_xor(p, off);
            if (lane == 0) red[wv] = p;     // waves 0..7
        }
        __syncthreads();

        // ---- E: gate partials (bf16 whhT) + ytil finalize
        {
            if (t < 2)
                ytil[t] = red[4 * t] + red[4 * t + 1] + red[4 * t + 2] + red[4 * t + 3]
                        + ys[t][ts] * fcws[256] + fcws[257];
            const int jck = wv >> 2, gb = wv & 3;   // i-chunk of 64, gate-block
            float4 a0 = {0,0,0,0}, a1 = {0,0,0,0};
            const unsigned short* wp = whhT + (size_t)(jck * 64) * 1024 + gb * 256 + lane * 4;
            #pragma unroll 8
            for (int i = 0; i < 64; ++i) {
                const float4 w4 = unpk(*(const uint2*)(wp + (size_t)i * 1024));
                const float2 h2 = *(const float2*)&hc2[jck * 64 + i][0];
                fma4(a0, h2.x, w4);
                fma4(a1, h2.y, w4);
            }
            *(float4*)&part[(jck * 2 + 0) * 1024 + gb * 256 + lane * 4] = a0;
            *(float4*)&part[(jck * 2 + 1) * 1024 + gb * 256 + lane * 4] = a1;
        }
        __syncthreads();
        if (t < 512) {        // reduce E + LSTM pointwise
            const int r = t >> 8, d = t & 255;
            float g0 = 0.f, g1 = 0.f, g2 = 0.f, g3 = 0.f;
            #pragma unroll
            for (int k = 0; k < 4; ++k) {
                const int base = (k * 2 + r) * 1024 + d;
                g0 += part[base];
                g1 += part[base + 256];
                g2 += part[base + 512];
                g3 += part[base + 768];
            }
            const float yt = ytil[r];
            const float gi = g0 + yt * wihs[d]       + biass[d];
            const float gf = g1 + yt * wihs[256 + d] + biass[256 + d];
            const float gg = g2 + yt * wihs[512 + d] + biass[512 + d];
            const float go = g3 + yt * wihs[768 + d] + biass[768 + d];
            const float c_old = hc2[256 + d][r];
            const float cn = fast_sigm(gf) * c_old + fast_sigm(gi) * fast_tanh(gg);
            const float hn = fast_sigm(go) * fast_tanh(cn);
            hc2[d][r] = hn;
            hc2[256 + d][r] = cn;
        }
        __syncthreads();
    }

    // ---- final: out[b] = [h, ctx] . fcf_w + fcf_b
    if (t < 512) {
        const int r = t >> 8, j = t & 255;
        float p = hc2[j][r] * fcfw[j] + ctx[r][j] * fcfw[256 + j];
        #pragma unroll
        for (int off = 32; off; off >>= 1) p += __shfl_xor(p, off);
        if (lane == 0) red[wv] = p;
    }
    __syncthreads();
    if (t < 2)
        out[b0 + t] = red[4 * t] + red[4 * t + 1] + red[4 * t + 2] + red[4 * t + 3] + fcfb[0];
}

extern "C" void kernel_launch(void* const* d_in, const int* in_sizes, int n_in,
                              void* d_out, int out_size, void* d_ws, size_t ws_size,
                              hipStream_t stream) {
    (void)in_sizes; (void)n_in; (void)out_size; (void)ws_size;
    const float* enc   = (const float*)d_in[0];   // [512][128][256]
    const float* yhist = (const float*)d_in[1];   // [512][128]
    const float* w1    = (const float*)d_in[2];   // [768][256]
    const float* b1    = (const float*)d_in[3];   // [256]
    const float* w2    = (const float*)d_in[4];   // [256]
    // d_in[5] = attn_b2: softmax-invariant, unused
    const float* wih   = (const float*)d_in[6];   // [1024]
    const float* whh   = (const float*)d_in[7];   // [1024][256]
    const float* bih   = (const float*)d_in[8];   // [1024]
    const float* bhh   = (const float*)d_in[9];   // [1024]
    const float* fcw   = (const float*)d_in[10];  // [257]
    const float* fcb   = (const float*)d_in[11];  // [1]
    const float* fcfw  = (const float*)d_in[12];  // [512]
    const float* fcfb  = (const float*)d_in[13];  // [1]
    float* out = (float*)d_out;

    unsigned short* prebf = (unsigned short*)d_ws;        // 16777216 bf16 (32MB)
    unsigned short* w1bf  = prebf + 16777216;             // 131072 bf16
    unsigned short* whhT  = w1bf + 131072;                // 262144 bf16
    float* biasg = (float*)(whhT + 262144);               // 1024 f

    prep_w1_bias<<<513, 256, 0, stream>>>(w1, bih, bhh, w1bf, biasg);
    transpose_whh_bf<<<64, 256, 0, stream>>>(whh, whhT);
    pre_enc_kernel<<<8192, 256, 0, stream>>>(enc, w1, b1, prebf);
    decoder_main<<<256, 1024, 0, stream>>>(enc, yhist, prebf, w1bf, w2, whhT,
                                           wih, biasg, fcw, fcb, fcfw, fcfb, out);
}